// Round 6
// baseline (754.666 us; speedup 1.0000x reference)
//
#include <hip/hip_runtime.h>

#define N_NODES 50000
#define N_EDGES 800000
#define F_NODE 32
#define F_EDGE 16
#define HID 128
#define DEPTH 4
#define N_GRAPHS 128

#define SCAN_BLOCKS ((N_NODES + 255) / 256)  // 196
#define NSTRIPS ((N_NODES + 31) / 32)        // 1563

#define NODES_PER_WAVE 8
#define WAVES_PER_BLOCK 4
#define AGG_BLOCKS ((N_NODES + NODES_PER_WAVE * WAVES_PER_BLOCK - 1) / (NODES_PER_WAVE * WAVES_PER_BLOCK))

using short8 = __attribute__((ext_vector_type(8))) short;
using f32x4 = __attribute__((ext_vector_type(4))) float;
using v2f = __attribute__((ext_vector_type(2))) float;

__device__ __forceinline__ float bf2f(unsigned short u) {
  return __uint_as_float((unsigned int)u << 16);
}
__device__ __forceinline__ unsigned short f2bf(float f) {
  unsigned int u = __float_as_uint(f);
  u += 0x7fffu + ((u >> 16) & 1u);  // round-to-nearest-even (no NaN in data)
  return (unsigned short)(u >> 16);
}
__device__ __forceinline__ v2f splat2(float s) { return (v2f){s, s}; }
__device__ __forceinline__ v2f unpack2(unsigned int u) {
  v2f r;
  r.x = __uint_as_float(u << 16);           // low ushort  -> col 2l
  r.y = __uint_as_float(u & 0xffff0000u);   // high ushort -> col 2l+1
  return r;
}
__device__ __forceinline__ unsigned int pack2(v2f v) {
  return ((unsigned int)f2bf(v.y) << 16) | (unsigned int)f2bf(v.x);
}

// ---------------- CSR build (by dst) ----------------

__global__ void hist_kernel(const int* __restrict__ dst, int* __restrict__ counts) {
  int e = blockIdx.x * blockDim.x + threadIdx.x;
  if (e < N_EDGES) atomicAdd(&counts[dst[e]], 1);
}

__device__ __forceinline__ int wave_incl_scan(int v, int lane) {
#pragma unroll
  for (int off = 1; off < 64; off <<= 1) {
    int u = __shfl_up(v, off, 64);
    if (lane >= off) v += u;
  }
  return v;
}

__global__ __launch_bounds__(256) void scan_sum_kernel(const int* __restrict__ counts,
                                                       int* __restrict__ bsums) {
  int i = blockIdx.x * 256 + threadIdx.x;
  int v = (i < N_NODES) ? counts[i] : 0;
  int lane = threadIdx.x & 63, wid = threadIdx.x >> 6;
#pragma unroll
  for (int off = 32; off > 0; off >>= 1) v += __shfl_down(v, off, 64);
  __shared__ int ws[4];
  if (lane == 0) ws[wid] = v;
  __syncthreads();
  if (threadIdx.x == 0) bsums[blockIdx.x] = ws[0] + ws[1] + ws[2] + ws[3];
}

__global__ __launch_bounds__(256) void scan_mid_kernel(const int* __restrict__ bsums,
                                                       int* __restrict__ boff,
                                                       int* __restrict__ row_ptr) {
  int t = threadIdx.x;
  int v = (t < SCAN_BLOCKS) ? bsums[t] : 0;
  int lane = t & 63, wid = t >> 6;
  int s = wave_incl_scan(v, lane);
  __shared__ int wsum[4];
  if (lane == 63) wsum[wid] = s;
  __syncthreads();
  int add = 0;
  for (int w = 0; w < wid; ++w) add += wsum[w];
  s += add;
  if (t < SCAN_BLOCKS) boff[t] = s - v;
  if (t == SCAN_BLOCKS - 1) row_ptr[N_NODES] = s;
}

__global__ __launch_bounds__(256) void scan_write_kernel(const int* __restrict__ counts,
                                                         const int* __restrict__ boff,
                                                         int* __restrict__ row_ptr,
                                                         int* __restrict__ cursor) {
  int i = blockIdx.x * 256 + threadIdx.x;
  int v = (i < N_NODES) ? counts[i] : 0;
  int lane = threadIdx.x & 63, wid = threadIdx.x >> 6;
  int s = wave_incl_scan(v, lane);
  __shared__ int wsum[4];
  if (lane == 63) wsum[wid] = s;
  __syncthreads();
  int add = boff[blockIdx.x];
  for (int w = 0; w < wid; ++w) add += wsum[w];
  int excl = s - v + add;
  if (i < N_NODES) {
    row_ptr[i] = excl;
    cursor[i] = excl;
  }
}

// ---- scatter: materialize src/edge_attr in dst-sorted order ----

__global__ void scatter_kernel(const int* __restrict__ src, const int* __restrict__ dst,
                               const float* __restrict__ edge_attr,
                               int* __restrict__ cursor, int* __restrict__ src_perm,
                               float* __restrict__ ea_perm) {
  int e = blockIdx.x * blockDim.x + threadIdx.x;
  if (e < N_EDGES) {
    int pos = atomicAdd(&cursor[dst[e]], 1);
    src_perm[pos] = src[e];
    const float4* in4 = (const float4*)(edge_attr + (size_t)e * F_EDGE);
    float4 a = in4[0], b = in4[1], c = in4[2], d = in4[3];
    float4* out4 = (float4*)(ea_perm + (size_t)pos * F_EDGE);
    out4[0] = a; out4[1] = b; out4[2] = c; out4[3] = d;
  }
}

// ---- weight repack: W[k][n] fp32 -> bf16 MFMA B-frag order ----
// frag f = t*4+k0 (t: 16-col tile, k0: 32-k step); lane l holds
// B[k = k0*32 + (l>>4)*8 + j][n = t*16 + (l&15)], j=0..7.

__global__ __launch_bounds__(256) void repack_w(const float* __restrict__ w1,
                                                const float* __restrict__ w2,
                                                unsigned short* __restrict__ wfrag) {
  int idx = blockIdx.x * 256 + threadIdx.x;
  if (idx >= 8 * 16384) return;
  int g = idx >> 14;
  int rem = idx & 16383;
  int f = rem >> 9;
  int lane = (rem >> 3) & 63;
  int j = rem & 7;
  int t = f >> 2, k0 = f & 3;
  int k = k0 * 32 + (lane >> 4) * 8 + j;
  int n = t * 16 + (lane & 15);
  int d = g >> 1;
  const float* W = (g & 1) ? (w2 + (size_t)d * HID * HID) : (w1 + (size_t)d * HID * HID);
  wfrag[idx] = f2bf(W[k * HID + n]);
}

// ---------------- init: h = relu(x @ init_w + init_b) -> bf16 h, h0 ----------------

__global__ __launch_bounds__(128) void init_kernel(const float* __restrict__ x,
                                                   const float* __restrict__ Wi,
                                                   const float* __restrict__ bi,
                                                   unsigned short* __restrict__ h,
                                                   unsigned short* __restrict__ h0) {
  int node = blockIdx.x;
  int j = threadIdx.x;
  __shared__ float xs[F_NODE];
  if (j < F_NODE) xs[j] = x[node * F_NODE + j];
  __syncthreads();
  float acc = bi[j];
#pragma unroll
  for (int k = 0; k < F_NODE; ++k) acc += xs[k] * Wi[k * HID + j];
  float v = acc > 0.f ? acc : 0.f;
  unsigned short b = f2bf(v);
  h[(size_t)node * HID + j] = b;
  h0[(size_t)node * HID + j] = b;
}

// ---- aggregation: z[n] = h[n] + sum relu(h[src] + ea @ We + be) ----
// 256-thread blocks = 4 waves; each wave owns NODES_PER_WAVE nodes (wave-uniform
// node index via readfirstlane keeps src/ea loads scalar). Lane l handles cols
// {2l,2l+1} packed fp32 (v_pk_fma_f32). Gather is software-pipelined one group
// ahead: 8 h-row loads in flight per wave.

__device__ __forceinline__ v2f edge_mlp2(const float4* __restrict__ ea,
                                         const v2f w[16], v2f ev) {
  float4 a0 = ea[0], a1 = ea[1], a2 = ea[2], a3 = ea[3];
  ev = __builtin_elementwise_fma(splat2(a0.x), w[0], ev);
  ev = __builtin_elementwise_fma(splat2(a0.y), w[1], ev);
  ev = __builtin_elementwise_fma(splat2(a0.z), w[2], ev);
  ev = __builtin_elementwise_fma(splat2(a0.w), w[3], ev);
  ev = __builtin_elementwise_fma(splat2(a1.x), w[4], ev);
  ev = __builtin_elementwise_fma(splat2(a1.y), w[5], ev);
  ev = __builtin_elementwise_fma(splat2(a1.z), w[6], ev);
  ev = __builtin_elementwise_fma(splat2(a1.w), w[7], ev);
  ev = __builtin_elementwise_fma(splat2(a2.x), w[8], ev);
  ev = __builtin_elementwise_fma(splat2(a2.y), w[9], ev);
  ev = __builtin_elementwise_fma(splat2(a2.z), w[10], ev);
  ev = __builtin_elementwise_fma(splat2(a2.w), w[11], ev);
  ev = __builtin_elementwise_fma(splat2(a3.x), w[12], ev);
  ev = __builtin_elementwise_fma(splat2(a3.y), w[13], ev);
  ev = __builtin_elementwise_fma(splat2(a3.z), w[14], ev);
  ev = __builtin_elementwise_fma(splat2(a3.w), w[15], ev);
  return ev;
}

__global__ __launch_bounds__(256) void agg_kernel(const unsigned short* __restrict__ h,
                                                  const int* __restrict__ src_perm,
                                                  const float* __restrict__ ea_perm,
                                                  const int* __restrict__ row_ptr,
                                                  const float* __restrict__ We,
                                                  const float* __restrict__ be,
                                                  unsigned short* __restrict__ z) {
  int lane = threadIdx.x & 63;
  int wv = __builtin_amdgcn_readfirstlane(threadIdx.x >> 6);
  const unsigned int* h32 = (const unsigned int*)h;
  unsigned int* z32 = (unsigned int*)z;
  v2f w[16];
#pragma unroll
  for (int t = 0; t < F_EDGE; ++t) {
    float2 wvv = *(const float2*)(We + t * HID + 2 * lane);
    w[t] = (v2f){wvv.x, wvv.y};
  }
  float2 bv = *(const float2*)(be + 2 * lane);
  v2f bj = (v2f){bv.x, bv.y};
  int n0 = (blockIdx.x * WAVES_PER_BLOCK + wv) * NODES_PER_WAVE;
  int n1 = n0 + NODES_PER_WAVE;
  if (n0 >= N_NODES) return;
  if (n1 > N_NODES) n1 = N_NODES;
  for (int node = n0; node < n1; ++node) {
    int beg = row_ptr[node], end = row_ptr[node + 1];
    v2f hn = unpack2(h32[(size_t)node * 64 + lane]);
    v2f acc = splat2(0.f);
    int i = beg;
    int ngrp = (end - beg) >> 2;
    if (ngrp > 0) {
      int s0 = src_perm[i + 0], s1 = src_perm[i + 1];
      int s2 = src_perm[i + 2], s3 = src_perm[i + 3];
      unsigned int g0 = h32[(size_t)s0 * 64 + lane];
      unsigned int g1 = h32[(size_t)s1 * 64 + lane];
      unsigned int g2 = h32[(size_t)s2 * 64 + lane];
      unsigned int g3 = h32[(size_t)s3 * 64 + lane];
      for (int gi = 1; gi < ngrp; ++gi) {
        int ii = i + gi * 4;
        // prefetch next group's gathers (8 loads in flight during compute)
        int t0 = src_perm[ii + 0], t1 = src_perm[ii + 1];
        int t2 = src_perm[ii + 2], t3 = src_perm[ii + 3];
        unsigned int p0 = h32[(size_t)t0 * 64 + lane];
        unsigned int p1 = h32[(size_t)t1 * 64 + lane];
        unsigned int p2 = h32[(size_t)t2 * 64 + lane];
        unsigned int p3 = h32[(size_t)t3 * 64 + lane];
        const float4* ea = (const float4*)(ea_perm + (size_t)(ii - 4) * F_EDGE);
        v2f m0 = unpack2(g0) + edge_mlp2(ea + 0, w, bj);
        v2f m1 = unpack2(g1) + edge_mlp2(ea + 4, w, bj);
        v2f m2 = unpack2(g2) + edge_mlp2(ea + 8, w, bj);
        v2f m3 = unpack2(g3) + edge_mlp2(ea + 12, w, bj);
        m0 = __builtin_elementwise_max(m0, splat2(0.f));
        m1 = __builtin_elementwise_max(m1, splat2(0.f));
        m2 = __builtin_elementwise_max(m2, splat2(0.f));
        m3 = __builtin_elementwise_max(m3, splat2(0.f));
        acc += m0 + m1 + m2 + m3;
        g0 = p0; g1 = p1; g2 = p2; g3 = p3;
      }
      const float4* ea = (const float4*)(ea_perm + (size_t)(i + (ngrp - 1) * 4) * F_EDGE);
      v2f m0 = unpack2(g0) + edge_mlp2(ea + 0, w, bj);
      v2f m1 = unpack2(g1) + edge_mlp2(ea + 4, w, bj);
      v2f m2 = unpack2(g2) + edge_mlp2(ea + 8, w, bj);
      v2f m3 = unpack2(g3) + edge_mlp2(ea + 12, w, bj);
      m0 = __builtin_elementwise_max(m0, splat2(0.f));
      m1 = __builtin_elementwise_max(m1, splat2(0.f));
      m2 = __builtin_elementwise_max(m2, splat2(0.f));
      m3 = __builtin_elementwise_max(m3, splat2(0.f));
      acc += m0 + m1 + m2 + m3;
      i += ngrp * 4;
    }
    for (; i < end; ++i) {
      int s = src_perm[i];
      unsigned int g = h32[(size_t)s * 64 + lane];
      const float4* ea = (const float4*)(ea_perm + (size_t)i * F_EDGE);
      v2f m = unpack2(g) + edge_mlp2(ea, w, bj);
      m = __builtin_elementwise_max(m, splat2(0.f));
      acc += m;
    }
    z32[(size_t)node * 64 + lane] = pack2(hn + acc);
  }
}

// ---- fused MLP: h = relu(relu(z@W1+b1)@W2+b2 + h0), per-depth, z1 via LDS ----
// 256 threads = 4 waves: wave covers 16 rows x 64 cols. Both W-frag sets in VGPRs.
// LDS tile [32][136] bf16: +8 pad keeps 16B alignment & conflict-free b128 reads.
// A-frag: lane holds A[m=lane&15][k=quad*8+j]; C/D: col=lane&15, row=quad*4+reg.

__global__ __launch_bounds__(256) void fused_mlp(const unsigned short* __restrict__ A,
                                                 const unsigned short* __restrict__ Wf1,
                                                 const unsigned short* __restrict__ Wf2,
                                                 const float* __restrict__ b1,
                                                 const float* __restrict__ b2,
                                                 const unsigned short* __restrict__ h0,
                                                 unsigned short* __restrict__ hout) {
  __shared__ unsigned short z1t[32][136];
  int tid = threadIdx.x;
  int lane = tid & 63;
  int wave = tid >> 6;
  int rowHalf = wave >> 1;
  int colHalf = wave & 1;
  int m15 = lane & 15, quad = lane >> 4;

  short8 bA[4][4], bB[4][4];
#pragma unroll
  for (int t = 0; t < 4; ++t)
#pragma unroll
    for (int k0 = 0; k0 < 4; ++k0) {
      size_t off = (((size_t)(colHalf * 4 + t) * 4 + k0) * 64 + lane) * 8;
      bA[t][k0] = *(const short8*)(Wf1 + off);
      bB[t][k0] = *(const short8*)(Wf2 + off);
    }
  float bs1[4], bs2[4];
#pragma unroll
  for (int t = 0; t < 4; ++t) {
    bs1[t] = b1[(colHalf * 4 + t) * 16 + m15];
    bs2[t] = b2[(colHalf * 4 + t) * 16 + m15];
  }

  for (int s = blockIdx.x; s < NSTRIPS; s += gridDim.x) {
    int row0 = s * 32 + rowHalf * 16;
    // ---- phase 1: z1 = relu(z @ W1 + b1) -> LDS ----
    int arow = row0 + m15;
    int rc = arow < N_NODES ? arow : N_NODES - 1;
    const unsigned short* ap = A + (size_t)rc * HID + quad * 8;
    short8 a0 = *(const short8*)(ap + 0);
    short8 a1 = *(const short8*)(ap + 32);
    short8 a2 = *(const short8*)(ap + 64);
    short8 a3 = *(const short8*)(ap + 96);
    f32x4 acc[4];
#pragma unroll
    for (int t = 0; t < 4; ++t) acc[t] = (f32x4){0.f, 0.f, 0.f, 0.f};
#pragma unroll
    for (int t = 0; t < 4; ++t) {
      acc[t] = __builtin_amdgcn_mfma_f32_16x16x32_bf16(a0, bA[t][0], acc[t], 0, 0, 0);
      acc[t] = __builtin_amdgcn_mfma_f32_16x16x32_bf16(a1, bA[t][1], acc[t], 0, 0, 0);
      acc[t] = __builtin_amdgcn_mfma_f32_16x16x32_bf16(a2, bA[t][2], acc[t], 0, 0, 0);
      acc[t] = __builtin_amdgcn_mfma_f32_16x16x32_bf16(a3, bA[t][3], acc[t], 0, 0, 0);
    }
#pragma unroll
    for (int t = 0; t < 4; ++t) {
      int col = (colHalf * 4 + t) * 16 + m15;
#pragma unroll
      for (int r = 0; r < 4; ++r) {
        float v = acc[t][r] + bs1[t];
        v = v > 0.f ? v : 0.f;
        z1t[rowHalf * 16 + quad * 4 + r][col] = f2bf(v);
      }
    }
    __syncthreads();
    // ---- phase 2: h = relu(z1 @ W2 + b2 + h0) ----
    const unsigned short* lp = &z1t[rowHalf * 16 + m15][quad * 8];
    short8 c0 = *(const short8*)(lp + 0);
    short8 c1 = *(const short8*)(lp + 32);
    short8 c2 = *(const short8*)(lp + 64);
    short8 c3 = *(const short8*)(lp + 96);
#pragma unroll
    for (int t = 0; t < 4; ++t) acc[t] = (f32x4){0.f, 0.f, 0.f, 0.f};
#pragma unroll
    for (int t = 0; t < 4; ++t) {
      acc[t] = __builtin_amdgcn_mfma_f32_16x16x32_bf16(c0, bB[t][0], acc[t], 0, 0, 0);
      acc[t] = __builtin_amdgcn_mfma_f32_16x16x32_bf16(c1, bB[t][1], acc[t], 0, 0, 0);
      acc[t] = __builtin_amdgcn_mfma_f32_16x16x32_bf16(c2, bB[t][2], acc[t], 0, 0, 0);
      acc[t] = __builtin_amdgcn_mfma_f32_16x16x32_bf16(c3, bB[t][3], acc[t], 0, 0, 0);
    }
#pragma unroll
    for (int t = 0; t < 4; ++t) {
      int col = (colHalf * 4 + t) * 16 + m15;
#pragma unroll
      for (int r = 0; r < 4; ++r) {
        int row = row0 + quad * 4 + r;
        if (row < N_NODES) {
          float v = acc[t][r] + bs2[t] + bf2f(h0[(size_t)row * HID + col]);
          v = v > 0.f ? v : 0.f;
          hout[(size_t)row * HID + col] = f2bf(v);
        }
      }
    }
    __syncthreads();  // LDS reused next strip
  }
}

// ---------------- pooling (batch is sorted), h in bf16 ----------------

__global__ __launch_bounds__(128) void pool_kernel(const unsigned short* __restrict__ h,
                                                   const int* __restrict__ batch,
                                                   float* __restrict__ pooled) {
  int j = threadIdx.x;
  int n0 = blockIdx.x * 256;
  int nend = n0 + 256;
  if (nend > N_NODES) nend = N_NODES;
  int cur = batch[n0];
  float acc = 0.f;
  for (int n = n0; n < nend; ++n) {
    int b = batch[n];
    if (b != cur) {
      atomicAdd(&pooled[cur * HID + j], acc);
      acc = 0.f;
      cur = b;
    }
    acc += bf2f(h[(size_t)n * HID + j]);
  }
  atomicAdd(&pooled[cur * HID + j], acc);
}

// ---------------- final: out[g] = pooled[g] . ffn_w + ffn_b ----------------

__global__ __launch_bounds__(128) void final_kernel(const float* __restrict__ pooled,
                                                    const float* __restrict__ fw,
                                                    const float* __restrict__ fb,
                                                    float* __restrict__ out) {
  int g = blockIdx.x;
  int j = threadIdx.x;
  float v = pooled[g * HID + j] * fw[j];
#pragma unroll
  for (int off = 32; off > 0; off >>= 1) v += __shfl_down(v, off, 64);
  __shared__ float tmp[2];
  if ((j & 63) == 0) tmp[j >> 6] = v;
  __syncthreads();
  if (j == 0) out[g] = tmp[0] + tmp[1] + fb[0];
}

// ---------------- launch ----------------

extern "C" void kernel_launch(void* const* d_in, const int* in_sizes, int n_in,
                              void* d_out, int out_size, void* d_ws, size_t ws_size,
                              hipStream_t stream) {
  const float* x = (const float*)d_in[0];
  const int* edge_index = (const int*)d_in[1];
  const float* edge_attr = (const float*)d_in[2];
  const int* batch = (const int*)d_in[3];
  const float* init_w = (const float*)d_in[4];
  const float* init_b = (const float*)d_in[5];
  const float* edge_w = (const float*)d_in[6];
  const float* edge_b = (const float*)d_in[7];
  const float* mlp_w1 = (const float*)d_in[8];
  const float* mlp_b1 = (const float*)d_in[9];
  const float* mlp_w2 = (const float*)d_in[10];
  const float* mlp_b2 = (const float*)d_in[11];
  const float* ffn_w = (const float*)d_in[12];
  const float* ffn_b = (const float*)d_in[13];

  const int* srcp = edge_index;
  const int* dstp = edge_index + N_EDGES;

  char* ws = (char*)d_ws;
  auto alloc = [&](size_t bytes) {
    char* p = ws;
    ws += (bytes + 255) & ~(size_t)255;
    return p;
  };
  unsigned short* h_bf = (unsigned short*)alloc((size_t)N_NODES * HID * 2);
  unsigned short* h0_bf = (unsigned short*)alloc((size_t)N_NODES * HID * 2);
  unsigned short* z_bf = (unsigned short*)alloc((size_t)N_NODES * HID * 2);
  unsigned short* wfrag = (unsigned short*)alloc((size_t)8 * 16384 * 2);
  int* row_ptr = (int*)alloc((size_t)(N_NODES + 1) * 4);
  int* cursor = (int*)alloc((size_t)N_NODES * 4);
  int* counts = (int*)alloc((size_t)N_NODES * 4);
  int* bsums = (int*)alloc((size_t)SCAN_BLOCKS * 4);
  int* boff = (int*)alloc((size_t)SCAN_BLOCKS * 4);
  int* src_perm = (int*)alloc((size_t)N_EDGES * 4);
  float* ea_perm = (float*)alloc((size_t)N_EDGES * F_EDGE * 4);
  float* pooled = (float*)alloc((size_t)N_GRAPHS * HID * 4);

  hipMemsetAsync(counts, 0, (size_t)N_NODES * 4, stream);
  hipMemsetAsync(pooled, 0, (size_t)N_GRAPHS * HID * 4, stream);

  hist_kernel<<<(N_EDGES + 255) / 256, 256, 0, stream>>>(dstp, counts);
  scan_sum_kernel<<<SCAN_BLOCKS, 256, 0, stream>>>(counts, bsums);
  scan_mid_kernel<<<1, 256, 0, stream>>>(bsums, boff, row_ptr);
  scan_write_kernel<<<SCAN_BLOCKS, 256, 0, stream>>>(counts, boff, row_ptr, cursor);
  scatter_kernel<<<(N_EDGES + 255) / 256, 256, 0, stream>>>(srcp, dstp, edge_attr,
                                                            cursor, src_perm, ea_perm);
  repack_w<<<512, 256, 0, stream>>>(mlp_w1, mlp_w2, wfrag);

  init_kernel<<<N_NODES, 128, 0, stream>>>(x, init_w, init_b, h_bf, h0_bf);

  for (int d = 0; d < DEPTH; ++d) {
    agg_kernel<<<AGG_BLOCKS, 256, 0, stream>>>(
        h_bf, src_perm, ea_perm, row_ptr, edge_w + (size_t)d * F_EDGE * HID,
        edge_b + (size_t)d * HID, z_bf);
    fused_mlp<<<512, 256, 0, stream>>>(z_bf, wfrag + (size_t)(2 * d) * 16384,
                                       wfrag + (size_t)(2 * d + 1) * 16384,
                                       mlp_b1 + (size_t)d * HID, mlp_b2 + (size_t)d * HID,
                                       h0_bf, h_bf);
  }

  pool_kernel<<<(N_NODES + 255) / 256, 128, 0, stream>>>(h_bf, batch, pooled);
  final_kernel<<<N_GRAPHS, 128, 0, stream>>>(pooled, ffn_w, ffn_b, (float*)d_out);
}